// Round 1
// baseline (588.567 us; speedup 1.0000x reference)
//
#include <hip/hip_runtime.h>

// ---------------------------------------------------------------------------
// StickyHDPHMMVI emission log-likelihood
// logB[bt,k] = c0_k + v_k . mu_t[bt] - 0.5 * sum_{d,e} E_k[d,e] * S0_bt[d,e]
// with S0 = mu muT + F FT + diag(var),  masked -> 0
// ---------------------------------------------------------------------------

#define BT_TOTAL 32768
#define DD 64
#define KK 33
#define RR 8

typedef __attribute__((ext_vector_type(8))) unsigned short us8;

__device__ __forceinline__ float bf2f(unsigned short u){
  union { unsigned int i; float f; } c; c.i = ((unsigned int)u) << 16; return c.f;
}
__device__ __forceinline__ unsigned short f2bf(float f){
  union { float f; unsigned int i; } c; c.f = f;
  unsigned int x = c.i;
  unsigned int r = (x + 0x7FFFu + ((x >> 16) & 1u)) >> 16;
  return (unsigned short)r;
}

__device__ __forceinline__ float digammaf_(float x){
  float r = 0.f;
  while (x < 6.f){ r -= 1.f / x; x += 1.f; }
  float xi = 1.f / x;
  float xi2 = xi * xi;
  return r + logf(x) - 0.5f * xi
         - xi2 * (0.083333333333f - xi2 * (0.0083333333333f - xi2 * 0.0039682539683f));
}

__device__ __forceinline__ float wsum64(float x){
  #pragma unroll
  for (int o = 32; o > 0; o >>= 1) x += __shfl_down(x, o);
  return x;  // valid in lane 0
}

// --------------------------- kernel A: per-k prep ---------------------------
__global__ __launch_bounds__(64) void prep_kernel(
    const float* __restrict__ mu_k, const float* __restrict__ Psi,
    const float* __restrict__ nu_a, const float* __restrict__ kap_a,
    float* __restrict__ Eo, float* __restrict__ vo, float* __restrict__ c0o)
{
  const int k = blockIdx.x;
  const int t = threadIdx.x;
  __shared__ float P[64][65];
  __shared__ float Mi[64][65];
  __shared__ float muk[64];

  const float* Pg = Psi + k * 4096;
  for (int i = t; i < 4096; i += 64) P[i >> 6][i & 63] = Pg[i];
  muk[t] = mu_k[k * 64 + t];
  __syncthreads();

  // left-looking Cholesky (lower triangle in place)
  for (int j = 0; j < 64; ++j){
    if (t == j){
      float s = P[j][j];
      for (int m = 0; m < j; ++m) s = fmaf(-P[j][m], P[j][m], s);
      P[j][j] = sqrtf(s);
    }
    __syncthreads();
    if (t > j){
      float s = P[t][j];
      for (int m = 0; m < j; ++m) s = fmaf(-P[t][m], P[j][m], s);
      P[t][j] = s / P[j][j];
    }
    __syncthreads();
  }

  float logdiag = logf(P[t][t]);

  // Mi = L^{-1}; thread t owns column t (only reads own column + P)
  Mi[t][t] = 1.f / P[t][t];
  for (int i = t + 1; i < 64; ++i){
    float s = 0.f;
    for (int m = t; m < i; ++m) s = fmaf(P[i][m], Mi[m][t], s);
    Mi[i][t] = -s / P[i][i];
  }
  __syncthreads();

  const float nu = nu_a[k];
  float vacc = 0.f;
  // E row t: E[t][e] = nu * sum_m Mi[m][t]*Mi[m][e]
  for (int e = 0; e < 64; ++e){
    int m0 = t > e ? t : e;
    float s = 0.f;
    for (int m = m0; m < 64; ++m) s = fmaf(Mi[m][t], Mi[m][e], s);
    float val = nu * s;
    Eo[k * 4096 + t * 64 + e] = val;
    vacc = fmaf(val, muk[e], vacc);
  }
  vo[k * 64 + t] = vacc;

  float c2   = wsum64(vacc * muk[t]);
  float dg   = wsum64(digammaf_((nu - (float)t) * 0.5f));
  float ldet = wsum64(logdiag);
  if (t == 0){
    const float LN2   = 0.69314718055994531f;
    const float LN2PI = 1.83787706640934548f;
    float logdetPsi = 2.f * ldet;
    float Elogdet = dg + 64.f * LN2 - logdetPsi;
    float cst = 0.5f * (Elogdet - 64.f * LN2PI);
    c0o[k] = cst - 0.5f * c2 - 32.f / kap_a[k];
  }
}

// --------------------------- kernel B: main ---------------------------------
__global__ __launch_bounds__(256, 2) void main_kernel(
    const float* __restrict__ mu_t, const float* __restrict__ var_t,
    const float* __restrict__ F_t, const unsigned char* __restrict__ maskb,
    const float* __restrict__ Eo, const float* __restrict__ vo,
    const float* __restrict__ c0o, float* __restrict__ out)
{
  __shared__ unsigned short sMu[32][64];    // bf16, e-blocks-of-8 XOR bt&7
  __shared__ unsigned short sVar[32][64];
  __shared__ unsigned short sFt[32][8][64]; // [bt][r][e] transposed, swizzled
  __shared__ float sSf[32 * 64];            // S0 row, 4-blocks XOR bt&15
  __shared__ float sEs[48][68];             // E[k][d][:] staged, rows 33..47 zero

  const int tid = threadIdx.x;
  const int bt0 = blockIdx.x * 32;

  // ---- mask format sniff (uniform across block, deterministic) ----
  const int l = tid & 63;
  const bool byteMask =
      __any((maskb[4 * l + 1] | maskb[4 * l + 2] | maskb[4 * l + 3]) != 0);

  // zero sEs once (covers pad rows 33..47)
  for (int i = tid; i < 48 * 68; i += 256) ((float*)sEs)[i] = 0.f;

  // ---- stage mu/var (bf16) ----
  for (int i = tid; i < 2048; i += 256){
    int bt = i >> 6, d = i & 63;
    int dsw = (((d >> 3) ^ (bt & 7)) << 3) | (d & 7);
    sMu[bt][dsw]  = f2bf(mu_t[bt0 * 64 + i]);
    sVar[bt][dsw] = f2bf(var_t[bt0 * 64 + i]);
  }
  // ---- stage F transposed (coalesced float4 global reads) ----
  {
    const float4* Fg = (const float4*)(F_t + (size_t)bt0 * 512);
    for (int i = tid; i < 4096; i += 256){
      float4 f = Fg[i];
      int bt  = i >> 7;
      int rem = i & 127;        // 128 float4 per bt
      int d   = rem >> 1;
      int rb  = (rem & 1) << 2; // r = rb..rb+3
      int dsw = (((d >> 3) ^ (bt & 7)) << 3) | (d & 7);
      sFt[bt][rb + 0][dsw] = f2bf(f.x);
      sFt[bt][rb + 1][dsw] = f2bf(f.y);
      sFt[bt][rb + 2][dsw] = f2bf(f.z);
      sFt[bt][rb + 3][dsw] = f2bf(f.w);
    }
  }
  __syncthreads();

  const int btg = tid & 15;          // contract: bt pair {2btg, 2btg+1}
  const int kg  = tid >> 4;          // contract: k = kg, kg+16, kg+32
  const int btA = 2 * btg, btB = btA + 1;
  float acc[2][3] = {{0.f, 0.f, 0.f}, {0.f, 0.f, 0.f}};

  const int bbt = tid >> 3;          // build: bt
  const int ebi = tid & 7;           // build: logical e-block
  const int bsw = ebi ^ (bbt & 7);   // swizzled e-block

  for (int d = 0; d < 64; ++d){
    // stage E[k][d][0:64] for all real k (L2-resident)
    {
      const float4* Eg4 = (const float4*)Eo;
      for (int i = tid; i < 528; i += 256){
        int k = i >> 4, e4 = i & 15;
        *(float4*)&sEs[k][e4 << 2] = Eg4[(k << 10) + (d << 4) + e4];
      }
    }
    // build S0 row d: s[e] = mu_d*mu_e + sum_r F[d,r]F[e,r] + (e==d)var_d
    {
      int dsw = (((d >> 3) ^ (bbt & 7)) << 3) | (d & 7);
      float md = bf2f(sMu[bbt][dsw]);
      float vd = bf2f(sVar[bbt][dsw]);
      float fd[8];
      #pragma unroll
      for (int r = 0; r < 8; ++r) fd[r] = bf2f(sFt[bbt][r][dsw]);
      us8 muv = *(const us8*)&sMu[bbt][bsw << 3];
      float s[8];
      #pragma unroll
      for (int q = 0; q < 8; ++q) s[q] = md * bf2f(muv[q]);
      #pragma unroll
      for (int r = 0; r < 8; ++r){
        us8 fv = *(const us8*)&sFt[bbt][r][bsw << 3];
        #pragma unroll
        for (int q = 0; q < 8; ++q) s[q] = fmaf(fd[r], bf2f(fv[q]), s[q]);
      }
      int e0 = ebi << 3;
      if (d >= e0 && d < e0 + 8) s[d - e0] += vd;
      float4 lo = make_float4(s[0], s[1], s[2], s[3]);
      float4 hi = make_float4(s[4], s[5], s[6], s[7]);
      int b4 = ebi << 1;
      *(float4*)&sSf[(bbt << 6) + (((b4)     ^ (bbt & 15)) << 2)] = lo;
      *(float4*)&sSf[(bbt << 6) + (((b4 + 1) ^ (bbt & 15)) << 2)] = hi;
    }
    __syncthreads();
    // contract: acc[p][j] += s[bt_p][e] * E[kg+16j][e]
    #pragma unroll
    for (int ec = 0; ec < 64; ec += 4){
      int b4 = ec >> 2;
      float4 s0 = *(const float4*)&sSf[(btA << 6) + ((b4 ^ (btA & 15)) << 2)];
      float4 s1 = *(const float4*)&sSf[(btB << 6) + ((b4 ^ (btB & 15)) << 2)];
      #pragma unroll
      for (int j = 0; j < 3; ++j){
        float4 Ev = *(const float4*)&sEs[kg + (j << 4)][ec];
        acc[0][j] = fmaf(s0.x, Ev.x, fmaf(s0.y, Ev.y, fmaf(s0.z, Ev.z, fmaf(s0.w, Ev.w, acc[0][j]))));
        acc[1][j] = fmaf(s1.x, Ev.x, fmaf(s1.y, Ev.y, fmaf(s1.z, Ev.z, fmaf(s1.w, Ev.w, acc[1][j]))));
      }
    }
    __syncthreads();
  }

  // stage v into (now free) sEs
  for (int i = tid; i < 2112; i += 256) sEs[i >> 6][i & 63] = vo[i];
  __syncthreads();

  #pragma unroll
  for (int p = 0; p < 2; ++p){
    int bt = btA + p;
    bool mk = byteMask ? (maskb[bt0 + bt] != 0)
                       : (maskb[(size_t)4 * (bt0 + bt)] != 0);
    #pragma unroll
    for (int j = 0; j < 3; ++j){
      int k = kg + (j << 4);
      if (k < 33){
        float vd = 0.f;
        for (int dd = 0; dd < 64; ++dd){
          int dsw = (((dd >> 3) ^ (bt & 7)) << 3) | (dd & 7);
          vd = fmaf(sEs[k][dd], bf2f(sMu[bt][dsw]), vd);
        }
        float res = c0o[k] + vd - 0.5f * acc[p][j];
        out[(size_t)(bt0 + bt) * 33 + k] = mk ? res : 0.f;
      }
    }
  }
}

// --------------------------- launch -----------------------------------------
extern "C" void kernel_launch(void* const* d_in, const int* in_sizes, int n_in,
                              void* d_out, int out_size, void* d_ws, size_t ws_size,
                              hipStream_t stream)
{
  const float* mu_t  = (const float*)d_in[0];
  const float* var_t = (const float*)d_in[1];
  const float* F_t   = (const float*)d_in[2];
  const float* mu_k  = (const float*)d_in[3];
  const float* Psi   = (const float*)d_in[4];
  const float* nu    = (const float*)d_in[5];
  const float* kap   = (const float*)d_in[6];
  const unsigned char* mask = (const unsigned char*)d_in[7];

  float* Eo  = (float*)d_ws;                 // 33*4096 f32
  float* vo  = Eo + 33 * 4096;               // 33*64 f32
  float* c0o = vo + 33 * 64;                 // 33 f32
  float* out = (float*)d_out;

  hipLaunchKernelGGL(prep_kernel, dim3(33), dim3(64), 0, stream,
                     mu_k, Psi, nu, kap, Eo, vo, c0o);
  hipLaunchKernelGGL(main_kernel, dim3(BT_TOTAL / 32), dim3(256), 0, stream,
                     mu_t, var_t, F_t, mask, Eo, vo, c0o, out);
}

// Round 2
// 242.937 us; speedup vs baseline: 2.4227x; 2.4227x over previous
//
#include <hip/hip_runtime.h>

// ---------------------------------------------------------------------------
// StickyHDPHMMVI emission log-likelihood, MFMA formulation:
// out[bt,k] = c0_k - 0.5 * sum_x A[bt,x] * B[k,x]
//   x in [0,4096): A = S0_bt[d,e] (mu muT + F FT), B = E_k[d,e]
//   x in [4096,4160): A = mu[d],  B = -2*v_k[d]      (v = E mu_k)
//   x in [4160,4224): A = var[d], B = E_k[d,d]       (diag trace term)
// flattening: x = (e>>5)*2048 + d*32 + (e&31)
// ---------------------------------------------------------------------------

#define KDIM 4224
#define NROW 48
#define BT_TOTAL 32768

typedef __attribute__((ext_vector_type(8))) short bf16x8;
typedef __attribute__((ext_vector_type(8))) unsigned short us8;
typedef __attribute__((ext_vector_type(4))) float f32x4;

__device__ __forceinline__ float bf2f(unsigned short u){
  union { unsigned int i; float f; } c; c.i = ((unsigned int)u) << 16; return c.f;
}
__device__ __forceinline__ unsigned short f2bfu(float f){
  union { float f; unsigned int i; } c; c.f = f;
  unsigned int x = c.i;
  return (unsigned short)((x + 0x7FFFu + ((x >> 16) & 1u)) >> 16);
}
__device__ __forceinline__ short f2bfs(float f){ return (short)f2bfu(f); }

__device__ __forceinline__ float digammaf_(float x){
  float r = 0.f;
  while (x < 6.f){ r -= 1.f / x; x += 1.f; }
  float xi = 1.f / x;
  float xi2 = xi * xi;
  return r + logf(x) - 0.5f * xi
         - xi2 * (0.083333333333f - xi2 * (0.0083333333333f - xi2 * 0.0039682539683f));
}

__device__ __forceinline__ float wsum64(float x){
  #pragma unroll
  for (int o = 32; o > 0; o >>= 1) x += __shfl_down(x, o);
  return x;  // valid in lane 0
}

// --------------------------- kernel A: per-k prep ---------------------------
__global__ __launch_bounds__(256) void prep_kernel(
    const float* __restrict__ mu_k, const float* __restrict__ Psi,
    const float* __restrict__ nu_a, const float* __restrict__ kap_a,
    short* __restrict__ Ebf, float* __restrict__ c0o)
{
  const int k = blockIdx.x;
  const int tid = threadIdx.x;
  short* Erow = Ebf + (size_t)k * KDIM;
  if (k >= 33){
    for (int i = tid; i < KDIM; i += 256) Erow[i] = 0;
    if (tid == 0) c0o[k] = 0.f;
    return;
  }
  __shared__ float P[64][65];
  __shared__ float Mi[64][65];
  __shared__ float Ef[64][64];
  __shared__ float muk[64];
  __shared__ float vsh[64];

  for (int i = tid; i < 4096; i += 256) P[i >> 6][i & 63] = Psi[(size_t)k * 4096 + i];
  if (tid < 64) muk[tid] = mu_k[k * 64 + tid];
  __syncthreads();

  const int t = tid;
  // left-looking Cholesky (wave 0 does the work; all threads hit barriers)
  for (int j = 0; j < 64; ++j){
    if (t == j){
      float s = P[j][j];
      for (int m = 0; m < j; ++m) s = fmaf(-P[j][m], P[j][m], s);
      P[j][j] = sqrtf(s);
    }
    __syncthreads();
    if (t > j && t < 64){
      float s = P[t][j];
      for (int m = 0; m < j; ++m) s = fmaf(-P[t][m], P[j][m], s);
      P[t][j] = s / P[j][j];
    }
    __syncthreads();
  }

  // Mi = L^{-1}, thread t owns column t
  if (t < 64){
    Mi[t][t] = 1.f / P[t][t];
    for (int i = t + 1; i < 64; ++i){
      float s = 0.f;
      for (int m = t; m < i; ++m) s = fmaf(P[i][m], Mi[m][t], s);
      Mi[i][t] = -s / P[i][i];
    }
  }
  __syncthreads();

  const float nu = nu_a[k];
  // E = nu * Mi^T Mi, 256-thread parallel
  for (int idx = tid; idx < 4096; idx += 256){
    int d = idx >> 6, e = idx & 63;
    int m0 = d > e ? d : e;
    float s = 0.f;
    for (int m = m0; m < 64; ++m) s = fmaf(Mi[m][d], Mi[m][e], s);
    Ef[d][e] = nu * s;
  }
  __syncthreads();
  // main 4096 slots, x-flattened, bf16
  for (int idx = tid; idx < 4096; idx += 256){
    int d = idx >> 6, e = idx & 63;
    Erow[((e >> 5) << 11) + (d << 5) + (e & 31)] = f2bfs(Ef[d][e]);
  }
  // v-slots and diag-slots
  if (t < 64){
    float v = 0.f;
    for (int e = 0; e < 64; ++e) v = fmaf(Ef[t][e], muk[e], v);
    vsh[t] = v;
    Erow[4096 + t] = f2bfs(-2.f * v);
    Erow[4160 + t] = f2bfs(Ef[t][t]);
  }
  __syncthreads();
  if (t < 64){
    float c2 = wsum64(vsh[t] * muk[t]);
    float dg = wsum64(digammaf_((nu - (float)t) * 0.5f));
    float ld = wsum64(logf(P[t][t]));
    if (t == 0){
      const float LN2   = 0.69314718055994531f;
      const float LN2PI = 1.83787706640934548f;
      float Elogdet = dg + 64.f * LN2 - 2.f * ld;
      float cst = 0.5f * (Elogdet - 64.f * LN2PI);
      c0o[k] = cst - 0.5f * c2 - 32.f / kap_a[k];
    }
  }
}

// --------------------------- kernel B: main (MFMA) --------------------------
__global__ __launch_bounds__(256, 2) void main_kernel(
    const float* __restrict__ mu_t, const float* __restrict__ var_t,
    const float* __restrict__ F_t, const unsigned char* __restrict__ maskb,
    const short* __restrict__ Ebf, const float* __restrict__ c0o,
    float* __restrict__ out)
{
  __shared__ unsigned short sF[64][64][8];   // [bt][d ^ (bt&7)][r]  bf16
  __shared__ unsigned short sMu[64][64];     // block-of-8 d-swizzle
  __shared__ unsigned short sVar[64][64];

  const int tid = threadIdx.x;
  const int l = tid & 63;
  const int bt0 = blockIdx.x * 64;

  // mask format sniff (bool bytes vs int32), block-uniform
  const bool byteMask =
      __any((maskb[4 * l + 1] | maskb[4 * l + 2] | maskb[4 * l + 3]) != 0);

  // ---- stage mu/var (bf16, block-8 d-swizzle) ----
  {
    const float4* mg = (const float4*)(mu_t + (size_t)bt0 * 64);
    const float4* vg = (const float4*)(var_t + (size_t)bt0 * 64);
    #pragma unroll
    for (int ii = 0; ii < 4; ++ii){
      int i = tid + ii * 256;
      float4 m4 = mg[i], v4 = vg[i];
      int bt = i >> 4, d = (i & 15) << 2;
      int dsw = (((d >> 3) ^ (bt & 7)) << 3) | (d & 7);
      ushort4 mm; mm.x = f2bfu(m4.x); mm.y = f2bfu(m4.y); mm.z = f2bfu(m4.z); mm.w = f2bfu(m4.w);
      ushort4 vv; vv.x = f2bfu(v4.x); vv.y = f2bfu(v4.y); vv.z = f2bfu(v4.z); vv.w = f2bfu(v4.w);
      *(ushort4*)&sMu[bt][dsw] = mm;
      *(ushort4*)&sVar[bt][dsw] = vv;
    }
    // ---- stage F (bf16, 16B r-vector d-swizzle) ----
    const float4* fg = (const float4*)(F_t + (size_t)bt0 * 512);
    #pragma unroll
    for (int ii = 0; ii < 32; ++ii){
      int i = tid + ii * 256;
      float4 f = fg[i];
      int bt = i >> 7, rem = i & 127, d = rem >> 1, rb = (rem & 1) << 2;
      int dsw = d ^ (bt & 7);
      ushort4 ff; ff.x = f2bfu(f.x); ff.y = f2bfu(f.y); ff.z = f2bfu(f.z); ff.w = f2bfu(f.w);
      *(ushort4*)&sF[bt][dsw][rb] = ff;
    }
  }
  __syncthreads();
  // no further barriers: waves run free

  const int w = tid >> 6;
  const int g = l >> 4;          // k-group within MFMA frag
  const int kc = l & 15;         // B column / A row-within-tile
  const int bt = w * 16 + kc;    // this lane's A row (bt within block)
  const int btSw = bt & 7;

  f32x4 acc0 = {0.f, 0.f, 0.f, 0.f};
  f32x4 acc1 = {0.f, 0.f, 0.f, 0.f};
  f32x4 acc2 = {0.f, 0.f, 0.f, 0.f};

  const short* bpBase = Ebf + (size_t)kc * KDIM + g * 8;

  for (int h = 0; h < 2; ++h){
    // per-half register cache: this lane's 8 e-columns of F and mu
    float Fe[8][8], mue[8];
    #pragma unroll
    for (int q = 0; q < 8; ++q){
      int e = h * 32 + g * 8 + q;
      us8 fv = *(const us8*)&sF[bt][e ^ btSw][0];
      #pragma unroll
      for (int r = 0; r < 8; ++r) Fe[q][r] = bf2f(fv[r]);
      int esw = (((e >> 3) ^ btSw) << 3) | (e & 7);
      mue[q] = bf2f(sMu[bt][esw]);
    }
    const short* bpH = bpBase + h * 2048;
    for (int d = 0; d < 64; ++d){
      const short* bp = bpH + d * 32;
      bf16x8 b0 = *(const bf16x8*)(bp);
      bf16x8 b1 = *(const bf16x8*)(bp + 16 * KDIM);
      bf16x8 b2 = *(const bf16x8*)(bp + 32 * KDIM);
      us8 fd8 = *(const us8*)&sF[bt][d ^ btSw][0];
      int dsw8 = (((d >> 3) ^ btSw) << 3) | (d & 7);
      float mud = bf2f(sMu[bt][dsw8]);
      float fd[8];
      #pragma unroll
      for (int r = 0; r < 8; ++r) fd[r] = bf2f(fd8[r]);
      float s[8];
      #pragma unroll
      for (int q = 0; q < 8; ++q) s[q] = mud * mue[q];
      #pragma unroll
      for (int r = 0; r < 8; ++r){
        #pragma unroll
        for (int q = 0; q < 8; ++q) s[q] = fmaf(fd[r], Fe[q][r], s[q]);
      }
      bf16x8 af;
      #pragma unroll
      for (int q = 0; q < 8; ++q) af[q] = f2bfs(s[q]);
      acc0 = __builtin_amdgcn_mfma_f32_16x16x32_bf16(af, b0, acc0, 0, 0, 0);
      acc1 = __builtin_amdgcn_mfma_f32_16x16x32_bf16(af, b1, acc1, 0, 0, 0);
      acc2 = __builtin_amdgcn_mfma_f32_16x16x32_bf16(af, b2, acc2, 0, 0, 0);
    }
  }

  // extension chunks: x in [4096,4224): A = mu (c=0,1), var (c=2,3)
  #pragma unroll
  for (int c = 0; c < 4; ++c){
    int d0 = (c & 1) * 32 + g * 8;
    int blk = (d0 >> 3) ^ btSw;
    const unsigned short* src = (c < 2) ? &sMu[bt][0] : &sVar[bt][0];
    bf16x8 af = *(const bf16x8*)&src[blk << 3];
    const short* bp = bpBase + 4096 + c * 32;
    bf16x8 b0 = *(const bf16x8*)(bp);
    bf16x8 b1 = *(const bf16x8*)(bp + 16 * KDIM);
    bf16x8 b2 = *(const bf16x8*)(bp + 32 * KDIM);
    acc0 = __builtin_amdgcn_mfma_f32_16x16x32_bf16(af, b0, acc0, 0, 0, 0);
    acc1 = __builtin_amdgcn_mfma_f32_16x16x32_bf16(af, b1, acc1, 0, 0, 0);
    acc2 = __builtin_amdgcn_mfma_f32_16x16x32_bf16(af, b2, acc2, 0, 0, 0);
  }

  // epilogue: D[m][n], m = g*4+reg (bt), n = kc (k); coalesced 16-float rows
  float c0a = c0o[kc];
  float c0b = c0o[16 + kc];
  float c0c = c0o[32];
  #pragma unroll
  for (int reg = 0; reg < 4; ++reg){
    int obt = bt0 + w * 16 + g * 4 + reg;
    bool mk = byteMask ? (maskb[obt] != 0) : (maskb[(size_t)4 * obt] != 0);
    float* op = out + (size_t)obt * 33;
    op[kc]      = mk ? fmaf(-0.5f, acc0[reg], c0a) : 0.f;
    op[16 + kc] = mk ? fmaf(-0.5f, acc1[reg], c0b) : 0.f;
    if (kc == 0) op[32] = mk ? fmaf(-0.5f, acc2[reg], c0c) : 0.f;
  }
}

// --------------------------- launch -----------------------------------------
extern "C" void kernel_launch(void* const* d_in, const int* in_sizes, int n_in,
                              void* d_out, int out_size, void* d_ws, size_t ws_size,
                              hipStream_t stream)
{
  const float* mu_t  = (const float*)d_in[0];
  const float* var_t = (const float*)d_in[1];
  const float* F_t   = (const float*)d_in[2];
  const float* mu_k  = (const float*)d_in[3];
  const float* Psi   = (const float*)d_in[4];
  const float* nu    = (const float*)d_in[5];
  const float* kap   = (const float*)d_in[6];
  const unsigned char* mask = (const unsigned char*)d_in[7];

  short* Ebf = (short*)d_ws;                                   // 48*4224 bf16
  float* c0o = (float*)((char*)d_ws + (size_t)NROW * KDIM * 2);
  float* outp = (float*)d_out;

  hipLaunchKernelGGL(prep_kernel, dim3(48), dim3(256), 0, stream,
                     mu_k, Psi, nu, kap, Ebf, c0o);
  hipLaunchKernelGGL(main_kernel, dim3(BT_TOTAL / 64), dim3(256), 0, stream,
                     mu_t, var_t, F_t, mask, Ebf, c0o, outp);
}